// Round 12
// baseline (930.783 us; speedup 1.0000x reference)
//
#include <hip/hip_runtime.h>
#include <hip/hip_bf16.h>

#define SEQ   512
#define BATCH 128
#define EMBD  256
#define HIDD  512
#define NCLS  16
#define VOCAB 32000

typedef unsigned long long u64;
typedef __attribute__((ext_vector_type(8))) short  short8;
typedef __attribute__((ext_vector_type(4))) float  f32x4;
typedef __attribute__((ext_vector_type(4))) int    i32x4;

__device__ __forceinline__ float bfu(unsigned short u) {
    return __uint_as_float(((unsigned int)u) << 16);
}
__device__ __forceinline__ unsigned short f2bf(float f) {
    __hip_bfloat16 h = __float2bfloat16(f);
    return *reinterpret_cast<unsigned short*>(&h);
}
__device__ __forceinline__ float rcp_fast(float x) {
    float r;
    asm("v_rcp_f32 %0, %1" : "=v"(r) : "v"(x));
    return r;
}
// byte0 of return = (i8)rint(127*tanh(x)).  No clamp needed: exp->inf => rcp->0
// => q=127; exp->0 => rcp(1)=1 => q=-127.  Magic-number rounding: fmaf result
// lies in [2^23,2^24) so RN gives the exact integer; byte0 = two's complement.
__device__ __forceinline__ unsigned q127b(float x) {
    const float e = __expf(x + x);
    const float r = rcp_fast(e + 1.f);
    const float f = fmaf(r, -254.f, 12583039.f);   // 12582912 + 127
    return __float_as_uint(f);
}
__device__ __forceinline__ unsigned pack4(unsigned a, unsigned b,
                                          unsigned c, unsigned d) {
    const unsigned lo = __builtin_amdgcn_perm(b, a, 0x0400u);      // [a0,b0,·,·]
    const unsigned hi = __builtin_amdgcn_perm(d, c, 0x0400u);      // [c0,d0,·,·]
    return __builtin_amdgcn_perm(hi, lo, 0x05040100u);             // [a0,b0,c0,d0]
}
__device__ __forceinline__ void ep_store(unsigned short* p, float v) { *p = f2bf(v); }

// LDS-only barrier: orders ds_read/ds_write across waves WITHOUT draining
// vmcnt — global (EP prefetch) loads stay in flight across the rendezvous.
__device__ __forceinline__ void lds_barrier() {
    __builtin_amdgcn_sched_barrier(0);
    asm volatile("s_waitcnt lgkmcnt(0)" ::: "memory");
    __builtin_amdgcn_s_barrier();
    __builtin_amdgcn_sched_barrier(0);
}

// ---------------------------------------------------------------------------
// scl layout (floats): [0]=absmax, [1]=sW*sh, [2]=absmax bits (u32, atomicMax)
__global__ void init_scl(float* __restrict__ scl) {
    if (threadIdx.x == 0) reinterpret_cast<unsigned*>(scl)[2] = 0u;
}

__global__ __launch_bounds__(256) void absmax_whh2(const float* __restrict__ W,
                                                   float* __restrict__ scl) {
    __shared__ float red[256];
    float m = 0.f;
    for (int i = blockIdx.x * 256 + threadIdx.x; i < (HIDD * HIDD) / 4; i += 64 * 256) {
        const float4 v = reinterpret_cast<const float4*>(W)[i];
        m = fmaxf(m, fmaxf(fmaxf(fabsf(v.x), fabsf(v.y)),
                           fmaxf(fabsf(v.z), fabsf(v.w))));
    }
    red[threadIdx.x] = m;
    __syncthreads();
    for (int s = 128; s > 0; s >>= 1) {
        if (threadIdx.x < s) red[threadIdx.x] = fmaxf(red[threadIdx.x], red[threadIdx.x + s]);
        __syncthreads();
    }
    if (threadIdx.x == 0)
        atomicMax(reinterpret_cast<unsigned*>(scl) + 2, __float_as_uint(red[0]));
}

// W_hh fp32 -> int8 row-major; thread 0 finalizes the scales.
__global__ void quant_whh2(const float* __restrict__ W, float* __restrict__ scl,
                           signed char* __restrict__ Wq) {
    const int i = blockIdx.x * 256 + threadIdx.x;
    const float am  = __uint_as_float(reinterpret_cast<unsigned*>(scl)[2]);
    const float inv = 127.f / am;
    Wq[i] = (signed char)(int)rintf(W[i] * inv);
    if (i == 0) { scl[0] = am; scl[1] = am / 16129.f; }   // (am/127)*(1/127)
}

// W_ih fp32 -> bf16 row-major.
__global__ void cvt_wih(const float* __restrict__ W, unsigned short* __restrict__ Wb) {
    const int i = blockIdx.x * 256 + threadIdx.x;
    Wb[i] = f2bf(W[i]);
}

// ---------------------------------------------------------------------------
// EP[v][j] = emb[v]·W_ih[j] + b_ih[j] + b_hh[j], stored bf16.  grid 500x256.
__global__ __launch_bounds__(256) void ep_gemm3(
    const float* __restrict__ emb, const unsigned short* __restrict__ Wih_b,
    const float* __restrict__ b_ih, const float* __restrict__ b_hh,
    unsigned short* __restrict__ EP) {
    const int w = threadIdx.x >> 6, l = threadIdx.x & 63;
    const int n = l & 15, lk = l >> 4;
    const int mtile = blockIdx.x * 4 + w;
    const int arow  = mtile * 16 + n;

    short8 areg[8];
    #pragma unroll
    for (int kk = 0; kk < 8; ++kk) {
        const int k0 = kk * 32 + lk * 8;
        const float4 a0 = *reinterpret_cast<const float4*>(emb + arow * EMBD + k0);
        const float4 a1 = *reinterpret_cast<const float4*>(emb + arow * EMBD + k0 + 4);
        short8 t;
        t[0]=(short)f2bf(a0.x); t[1]=(short)f2bf(a0.y); t[2]=(short)f2bf(a0.z); t[3]=(short)f2bf(a0.w);
        t[4]=(short)f2bf(a1.x); t[5]=(short)f2bf(a1.y); t[6]=(short)f2bf(a1.z); t[7]=(short)f2bf(a1.w);
        areg[kk] = t;
    }

    for (int nt = 0; nt < 32; ++nt) {
        const int col  = nt * 16 + n;
        const float bias = b_ih[col] + b_hh[col];
        f32x4 accA = {0.f,0.f,0.f,0.f}, accB = {0.f,0.f,0.f,0.f};
        #pragma unroll
        for (int kk = 0; kk < 8; ++kk) {
            const short8 bb = *reinterpret_cast<const short8*>(
                Wih_b + (size_t)col * EMBD + kk * 32 + lk * 8);
            if (kk & 1) accB = __builtin_amdgcn_mfma_f32_16x16x32_bf16(areg[kk], bb, accB, 0, 0, 0);
            else        accA = __builtin_amdgcn_mfma_f32_16x16x32_bf16(areg[kk], bb, accA, 0, 0, 0);
        }
        const f32x4 ac = accA + accB;
        #pragma unroll
        for (int r = 0; r < 4; ++r)
            ep_store(EP + (size_t)(mtile * 16 + lk * 4 + r) * HIDD + col, ac[r] + bias);
    }
}

// ---------------------------------------------------------------------------
// int8 weights-stationary RNN, 4 waves/SIMD for TLP.
// grid = 8, 1024 thr (16 waves, 4/SIMD, 1 block/CU). Wave w owns cols
// [w*32, w*32+32): weights in 64 regs/thread (i8 A-frags). h int8
// double-buffered in LDS (2 x 8 KB), 16B-granule XOR swizzle. LDS-only
// barrier; EP prefetch spans steps via alternating register sets.
__global__ __launch_bounds__(1024, 4) void rnn12(
    const int*            __restrict__ x,
    const signed char*    __restrict__ Wq,    // int8 [512][512]
    const float*          __restrict__ scl,   // [1] = sW*sh
    const unsigned short* __restrict__ EP,    // bf16 [VOCAB][512]
    const float*          __restrict__ W_fc,
    const float*          __restrict__ b_fc,
    float*                __restrict__ out) {

    __shared__ __align__(16) char hq[2 * 16 * 512];   // 16 KB total

    const int tid = threadIdx.x;
    const int w   = tid >> 6, l = tid & 63;
    const int n   = l & 15,  lk = l >> 4;
    const int b0  = blockIdx.x * 16;
    const int jw  = w * 32;
    const float fs = scl[1];

    // loop-invariant LDS byte offsets (into buffer 0)
    int rdA[8];
    #pragma unroll
    for (int kf = 0; kf < 8; ++kf) {
        const int g = kf * 4 + lk;
        rdA[kf] = n * 512 + ((g ^ n) << 4);
    }
    int wrA[2];
    #pragma unroll
    for (int tau = 0; tau < 2; ++tau) {
        const int j0 = jw + tau * 16 + lk * 4;
        wrA[tau] = n * 512 + (((j0 >> 4) ^ n) << 4) + (j0 & 15);
    }

    // per-lane EP base (this thread always reads the same 2 ushort4 slots of a row)
    const unsigned short* const epb = EP + jw + lk * 4;

    // ---- register-resident int8 A-frags: wave's 32 weight rows ----
    i32x4 af[2][8];
    #pragma unroll
    for (int tau = 0; tau < 2; ++tau)
        #pragma unroll
        for (int kf = 0; kf < 8; ++kf)
            af[tau][kf] = *reinterpret_cast<const i32x4*>(
                Wq + (size_t)(jw + tau * 16 + n) * HIDD + kf * 64 + lk * 16);

    // ---- t = 0: h1 = tanh(EP[tok0]) -> buffer 1 ----
    {
        const int tok0 = x[b0 + n];
        #pragma unroll
        for (int tau = 0; tau < 2; ++tau) {
            const ushort4 v = *reinterpret_cast<const ushort4*>(
                epb + (size_t)tok0 * HIDD + tau * 16);
            *reinterpret_cast<unsigned*>(hq + 8192 + wrA[tau]) =
                pack4(q127b(bfu(v.x)), q127b(bfu(v.y)),
                      q127b(bfu(v.z)), q127b(bfu(v.w)));
        }
    }

    // ---- prefetch EP for t=1 (-> pcA) + token for t=2 (-> tokB) ----
    ushort4 pcA[2], pcB[2];
    int tokA, tokB;
    {
        const int tok1 = x[BATCH + b0 + n];
        #pragma unroll
        for (int tau = 0; tau < 2; ++tau)
            pcA[tau] = *reinterpret_cast<const ushort4*>(
                epb + (size_t)tok1 * HIDD + tau * 16);
    }
    tokB = x[2 * BATCH + b0 + n];
    __syncthreads();

// FIN: dequant + EP + tanh->q127 + perm-pack + b32 publish at write offset WO.
#define FIN(tau, acc, PC, WO)                                                 \
    {                                                                         \
        const unsigned q0 = q127b(fmaf((float)acc[0], fs, bfu(PC[tau].x)));   \
        const unsigned q1 = q127b(fmaf((float)acc[1], fs, bfu(PC[tau].y)));   \
        const unsigned q2 = q127b(fmaf((float)acc[2], fs, bfu(PC[tau].z)));   \
        const unsigned q3 = q127b(fmaf((float)acc[3], fs, bfu(PC[tau].w)));   \
        *reinterpret_cast<unsigned*>(hq + (WO) + wrA[tau]) = pack4(q0, q1, q2, q3); \
    }
// One RNN step. ro/wo compile-time. PC = EP values for THIS step; PN = set to
// prefetch into (consumed next step); TOKIN = token whose EP row to prefetch;
// TOKOUT receives the token for two steps ahead. B staged in two tranches of
// 4 frags to cap register pressure at the 128-reg/4-wave tier.
#define STEP(ro, wo, PC, PN, TOKIN, TOKOUT, TNEXT)                            \
    {                                                                         \
        PN[0] = *reinterpret_cast<const ushort4*>(                            \
            epb + (size_t)(TOKIN) * HIDD);                                    \
        PN[1] = *reinterpret_cast<const ushort4*>(                            \
            epb + (size_t)(TOKIN) * HIDD + 16);                               \
        const int tn_ = (TNEXT) > 511 ? 511 : (TNEXT);                        \
        TOKOUT = x[tn_ * BATCH + b0 + n];                                     \
        i32x4 a0 = {0,0,0,0}, a1 = {0,0,0,0};                                 \
        {                                                                     \
            i32x4 Bt[4];                                                      \
            _Pragma("unroll")                                                 \
            for (int kf = 0; kf < 4; ++kf)                                    \
                Bt[kf] = *reinterpret_cast<const i32x4*>(hq + (ro) + rdA[kf]);\
            _Pragma("unroll")                                                 \
            for (int kf = 0; kf < 4; ++kf) {                                  \
                a0 = __builtin_amdgcn_mfma_i32_16x16x64_i8(af[0][kf], Bt[kf], a0, 0, 0, 0); \
                a1 = __builtin_amdgcn_mfma_i32_16x16x64_i8(af[1][kf], Bt[kf], a1, 0, 0, 0); \
            }                                                                 \
        }                                                                     \
        {                                                                     \
            i32x4 Bt[4];                                                      \
            _Pragma("unroll")                                                 \
            for (int kf = 0; kf < 4; ++kf)                                    \
                Bt[kf] = *reinterpret_cast<const i32x4*>(hq + (ro) + rdA[kf + 4]);\
            _Pragma("unroll")                                                 \
            for (int kf = 0; kf < 4; ++kf) {                                  \
                a0 = __builtin_amdgcn_mfma_i32_16x16x64_i8(af[0][kf + 4], Bt[kf], a0, 0, 0, 0); \
                a1 = __builtin_amdgcn_mfma_i32_16x16x64_i8(af[1][kf + 4], Bt[kf], a1, 0, 0, 0); \
            }                                                                 \
        }                                                                     \
        FIN(0, a0, PC, wo) FIN(1, a1, PC, wo)                                 \
        lds_barrier();                                                        \
    }

    for (int tp = 0; tp < 256; ++tp) {
        const int t = 2 * tp + 1;              // 1,3,...,511
        // odd step: read buf1, write buf0; uses pcA, prefetch -> pcB
        STEP(8192, 0, pcA, pcB, tokB, tokA, t + 2)
        if (t == 511) break;
        // even step: read buf0, write buf1; uses pcB, prefetch -> pcA
        STEP(0, 8192, pcB, pcA, tokA, tokB, t + 3)
    }
#undef STEP
#undef FIN

    // ---- FC epilogue: h_512 is in buffer 0 (last write of t=511) ----
    if (tid < 256) {
        const int n2 = tid >> 4, c = tid & 15;
        float dot = 0.f;
        for (int g = 0; g < 32; ++g) {
            const char* p = hq + n2 * 512 + ((g ^ n2) << 4);
            const float* wf = W_fc + c * HIDD + g * 16;
            #pragma unroll
            for (int i = 0; i < 16; ++i)
                dot += (float)((signed char)p[i]) * wf[i];
        }
        out[(b0 + n2) * NCLS + c] = dot * (1.f / 127.f) + b_fc[c];
    }
}

// ---------------------------------------------------------------------------
// Tier-C fallback (round-1, known good) for small ws.
__global__ void cvt_kernel(const float* __restrict__ W_ih,
                           const float* __restrict__ W_hh,
                           const float* __restrict__ b_ih,
                           const float* __restrict__ b_hh,
                           unsigned short* __restrict__ Wpk,
                           unsigned short* __restrict__ Wipk,
                           float* __restrict__ bias) {
    const int NW = HIDD * HIDD;
    const int NI = HIDD * EMBD;
    int gid = blockIdx.x * blockDim.x + threadIdx.x;
    if (gid < NW) {
        int j = gid >> 9, k = gid & (HIDD - 1);
        Wpk[((k >> 2) * HIDD + j) * 4 + (k & 3)] = f2bf(W_hh[gid]);
    } else if (gid < NW + NI) {
        int g2 = gid - NW, j = g2 >> 8, e = g2 & (EMBD - 1);
        Wipk[((e >> 2) * HIDD + j) * 4 + (e & 3)] = f2bf(W_ih[g2]);
    } else if (gid < NW + NI + HIDD) {
        int j = gid - NW - NI;
        bias[j] = b_ih[j] + b_hh[j];
    }
}

__global__ __launch_bounds__(512) void rnn_kernel(
    const int* __restrict__ x, const float* __restrict__ emb,
    const unsigned short* __restrict__ Wpk, const unsigned short* __restrict__ Wipk,
    const float* __restrict__ bias, const float* __restrict__ W_fc,
    const float* __restrict__ b_fc, float* __restrict__ out) {
    __shared__ __align__(16) float hL[HIDD];
    __shared__ __align__(16) float xe[EMBD];
    __shared__ float red[512];
    const int tid = threadIdx.x, b = blockIdx.x, j = tid;
    hL[j] = 0.0f;
    const float bj = bias[j];
    const ushort4* Wp4 = reinterpret_cast<const ushort4*>(Wpk);
    const ushort4* Wi4 = reinterpret_cast<const ushort4*>(Wipk);
    for (int t = 0; t < SEQ; ++t) {
        const int tok = x[t * BATCH + b];
        if (tid < EMBD) xe[tid] = emb[tok * EMBD + tid];
        __syncthreads();
        float a0 = bj, a1 = 0.0f;
        #pragma unroll 8
        for (int e4 = 0; e4 < EMBD / 4; ++e4) {
            const float4 xv = *reinterpret_cast<const float4*>(&xe[e4 * 4]);
            const ushort4 ww = Wi4[e4 * HIDD + j];
            a0 += xv.x * bfu(ww.x) + xv.y * bfu(ww.y);
            a1 += xv.z * bfu(ww.z) + xv.w * bfu(ww.w);
        }
        #pragma unroll 8
        for (int k4 = 0; k4 < HIDD / 4; ++k4) {
            const float4 hvv = *reinterpret_cast<const float4*>(&hL[k4 * 4]);
            const ushort4 ww = Wp4[k4 * HIDD + j];
            a0 += hvv.x * bfu(ww.x) + hvv.y * bfu(ww.y);
            a1 += hvv.z * bfu(ww.z) + hvv.w * bfu(ww.w);
        }
        __syncthreads();
        hL[j] = tanhf(a0 + a1);
    }
    __syncthreads();
    {
        const int c = tid >> 5, ks = tid & 31;
        float p = 0.0f;
        #pragma unroll
        for (int jj = 0; jj < HIDD / 32; ++jj) {
            const int jd = ks * (HIDD / 32) + jj;
            p += hL[jd] * W_fc[c * HIDD + jd];
        }
        red[tid] = p;
        __syncthreads();
        if (tid < NCLS) {
            float ss = b_fc[tid];
            #pragma unroll
            for (int i = 0; i < 32; ++i) ss += red[tid * 32 + i];
            out[b * NCLS + tid] = ss;
        }
    }
}

// ---------------------------------------------------------------------------
extern "C" void kernel_launch(void* const* d_in, const int* in_sizes, int n_in,
                              void* d_out, int out_size, void* d_ws, size_t ws_size,
                              hipStream_t stream) {
    const int*   x    = (const int*)  d_in[0];
    const float* emb  = (const float*)d_in[1];
    const float* W_ih = (const float*)d_in[2];
    const float* W_hh = (const float*)d_in[3];
    const float* b_ih = (const float*)d_in[4];
    const float* b_hh = (const float*)d_in[5];
    const float* W_fc = (const float*)d_in[6];
    const float* b_fc = (const float*)d_in[7];
    float* out = (float*)d_out;

    const size_t QW_B  = (size_t)HIDD * HIDD;       // 256 KB int8 W_hh
    const size_t SCL_B = 16;                        // scale slots
    const size_t WIH_B = (size_t)HIDD * EMBD * 2;   // 256 KB bf16 W_ih
    const size_t EPN   = (size_t)VOCAB * HIDD;
    const size_t HEAD  = QW_B + SCL_B + WIH_B;

    if (ws_size >= HEAD + EPN * 2) {
        signed char*    Wq    = (signed char*)d_ws;
        float*          scl   = (float*)((char*)d_ws + QW_B);
        unsigned short* Wih_b = (unsigned short*)((char*)d_ws + QW_B + SCL_B);
        unsigned short* EP    = (unsigned short*)((char*)d_ws + HEAD);
        init_scl<<<1, 64, 0, stream>>>(scl);
        absmax_whh2<<<64, 256, 0, stream>>>(W_hh, scl);
        quant_whh2<<<(HIDD * HIDD) / 256, 256, 0, stream>>>(W_hh, scl, Wq);
        cvt_wih<<<(HIDD * EMBD) / 256, 256, 0, stream>>>(W_ih, Wih_b);
        ep_gemm3<<<VOCAB / 64, 256, 0, stream>>>(emb, Wih_b, b_ih, b_hh, EP);
        rnn12<<<8, 1024, 0, stream>>>(x, Wq, scl, EP, W_fc, b_fc, out);
    } else {
        unsigned short* Wpk  = (unsigned short*)d_ws;
        unsigned short* Wipk = Wpk + HIDD * HIDD;
        float*          bias = (float*)(Wipk + HIDD * EMBD);
        const int total = HIDD * HIDD + HIDD * EMBD + HIDD;
        cvt_kernel<<<(total + 255) / 256, 256, 0, stream>>>(W_ih, W_hh, b_ih, b_hh, Wpk, Wipk, bias);
        rnn_kernel<<<BATCH, 512, 0, stream>>>(x, emb, Wpk, Wipk, bias, W_fc, b_fc, out);
    }
}

// Round 13
// 907.485 us; speedup vs baseline: 1.0257x; 1.0257x over previous
//
#include <hip/hip_runtime.h>
#include <hip/hip_bf16.h>

#define SEQ   512
#define BATCH 128
#define EMBD  256
#define HIDD  512
#define NCLS  16
#define VOCAB 32000

typedef unsigned long long u64;
typedef __attribute__((ext_vector_type(8))) short  short8;
typedef __attribute__((ext_vector_type(4))) float  f32x4;
typedef __attribute__((ext_vector_type(4))) int    i32x4;

__device__ __forceinline__ float bfu(unsigned short u) {
    return __uint_as_float(((unsigned int)u) << 16);
}
__device__ __forceinline__ unsigned short f2bf(float f) {
    __hip_bfloat16 h = __float2bfloat16(f);
    return *reinterpret_cast<unsigned short*>(&h);
}
__device__ __forceinline__ float rcp_fast(float x) {
    float r;
    asm("v_rcp_f32 %0, %1" : "=v"(r) : "v"(x));
    return r;
}
// byte0 of return = (i8)rint(127*tanh(x)).  No clamp needed: exp->inf => rcp->0
// => q=127; exp->0 => rcp(1)=1 => q=-127.  Magic-number rounding: fmaf result
// lies in [2^23,2^24) so RN gives the exact integer; byte0 = two's complement.
__device__ __forceinline__ unsigned q127b(float x) {
    const float e = __expf(x + x);
    const float r = rcp_fast(e + 1.f);
    const float f = fmaf(r, -254.f, 12583039.f);   // 12582912 + 127
    return __float_as_uint(f);
}
__device__ __forceinline__ unsigned pack4(unsigned a, unsigned b,
                                          unsigned c, unsigned d) {
    const unsigned lo = __builtin_amdgcn_perm(b, a, 0x0400u);      // [a0,b0,·,·]
    const unsigned hi = __builtin_amdgcn_perm(d, c, 0x0400u);      // [c0,d0,·,·]
    return __builtin_amdgcn_perm(hi, lo, 0x05040100u);             // [a0,b0,c0,d0]
}
__device__ __forceinline__ void ep_store(unsigned short* p, float v) { *p = f2bf(v); }

// LDS-only barrier: orders ds_read/ds_write across waves WITHOUT draining
// vmcnt — global (EP prefetch) loads stay in flight across the rendezvous.
__device__ __forceinline__ void lds_barrier() {
    __builtin_amdgcn_sched_barrier(0);
    asm volatile("s_waitcnt lgkmcnt(0)" ::: "memory");
    __builtin_amdgcn_s_barrier();
    __builtin_amdgcn_sched_barrier(0);
}

// ---------------------------------------------------------------------------
// scl layout (floats): [0]=absmax, [1]=sW*sh, [2]=absmax bits (u32, atomicMax)
__global__ void init_scl(float* __restrict__ scl) {
    if (threadIdx.x == 0) reinterpret_cast<unsigned*>(scl)[2] = 0u;
}

__global__ __launch_bounds__(256) void absmax_whh2(const float* __restrict__ W,
                                                   float* __restrict__ scl) {
    __shared__ float red[256];
    float m = 0.f;
    for (int i = blockIdx.x * 256 + threadIdx.x; i < (HIDD * HIDD) / 4; i += 64 * 256) {
        const float4 v = reinterpret_cast<const float4*>(W)[i];
        m = fmaxf(m, fmaxf(fmaxf(fabsf(v.x), fabsf(v.y)),
                           fmaxf(fabsf(v.z), fabsf(v.w))));
    }
    red[threadIdx.x] = m;
    __syncthreads();
    for (int s = 128; s > 0; s >>= 1) {
        if (threadIdx.x < s) red[threadIdx.x] = fmaxf(red[threadIdx.x], red[threadIdx.x + s]);
        __syncthreads();
    }
    if (threadIdx.x == 0)
        atomicMax(reinterpret_cast<unsigned*>(scl) + 2, __float_as_uint(red[0]));
}

// W_hh fp32 -> int8 AND W_ih fp32 -> bf16 in one launch; thread 0 finalizes
// the scales. grid covers HIDD*HIDD + HIDD*EMBD elements.
__global__ void prep_weights(const float* __restrict__ W_hh,
                             const float* __restrict__ W_ih,
                             float* __restrict__ scl,
                             signed char* __restrict__ Wq,
                             unsigned short* __restrict__ Wb) {
    const int i = blockIdx.x * 256 + threadIdx.x;
    const float am = __uint_as_float(reinterpret_cast<unsigned*>(scl)[2]);
    if (i < HIDD * HIDD) {
        Wq[i] = (signed char)(int)rintf(W_hh[i] * (127.f / am));
    } else if (i < HIDD * HIDD + HIDD * EMBD) {
        const int j = i - HIDD * HIDD;
        Wb[j] = f2bf(W_ih[j]);
    }
    if (i == 0) { scl[0] = am; scl[1] = am / 16129.f; }   // (am/127)*(1/127)
}

// ---------------------------------------------------------------------------
// EP[v][j] = emb[v]·W_ih[j] + b_ih[j] + b_hh[j], stored bf16.  grid 500x256.
__global__ __launch_bounds__(256) void ep_gemm3(
    const float* __restrict__ emb, const unsigned short* __restrict__ Wih_b,
    const float* __restrict__ b_ih, const float* __restrict__ b_hh,
    unsigned short* __restrict__ EP) {
    const int w = threadIdx.x >> 6, l = threadIdx.x & 63;
    const int n = l & 15, lk = l >> 4;
    const int mtile = blockIdx.x * 4 + w;
    const int arow  = mtile * 16 + n;

    short8 areg[8];
    #pragma unroll
    for (int kk = 0; kk < 8; ++kk) {
        const int k0 = kk * 32 + lk * 8;
        const float4 a0 = *reinterpret_cast<const float4*>(emb + arow * EMBD + k0);
        const float4 a1 = *reinterpret_cast<const float4*>(emb + arow * EMBD + k0 + 4);
        short8 t;
        t[0]=(short)f2bf(a0.x); t[1]=(short)f2bf(a0.y); t[2]=(short)f2bf(a0.z); t[3]=(short)f2bf(a0.w);
        t[4]=(short)f2bf(a1.x); t[5]=(short)f2bf(a1.y); t[6]=(short)f2bf(a1.z); t[7]=(short)f2bf(a1.w);
        areg[kk] = t;
    }

    for (int nt = 0; nt < 32; ++nt) {
        const int col  = nt * 16 + n;
        const float bias = b_ih[col] + b_hh[col];
        f32x4 accA = {0.f,0.f,0.f,0.f}, accB = {0.f,0.f,0.f,0.f};
        #pragma unroll
        for (int kk = 0; kk < 8; ++kk) {
            const short8 bb = *reinterpret_cast<const short8*>(
                Wih_b + (size_t)col * EMBD + kk * 32 + lk * 8);
            if (kk & 1) accB = __builtin_amdgcn_mfma_f32_16x16x32_bf16(areg[kk], bb, accB, 0, 0, 0);
            else        accA = __builtin_amdgcn_mfma_f32_16x16x32_bf16(areg[kk], bb, accA, 0, 0, 0);
        }
        const f32x4 ac = accA + accB;
        #pragma unroll
        for (int r = 0; r < 4; ++r)
            ep_store(EP + (size_t)(mtile * 16 + lk * 4 + r) * HIDD + col, ac[r] + bias);
    }
}

// ---------------------------------------------------------------------------
// int8 weights-stationary RNN; r11 + per-wave kf rotation (de-phases the
// post-barrier LDS burst and MFMA start across the 8 waves) + setprio(1)
// around the MFMA block. grid = 8, 512 thr (8 waves, 2/SIMD). Wave w owns
// cols [w*64,w*64+64): all weights in 128 regs/thread (i8 A-frags, storage
// rotated so loop indices stay compile-time). h int8 double-buffered in LDS
// (2 x 8 KB), 16B-granule XOR swizzle. LDS-only barrier; EP prefetch spans
// steps via alternating register sets.
__global__ __launch_bounds__(512, 2) void rnn13(
    const int*            __restrict__ x,
    const signed char*    __restrict__ Wq,    // int8 [512][512]
    const float*          __restrict__ scl,   // [1] = sW*sh
    const unsigned short* __restrict__ EP,    // bf16 [VOCAB][512]
    const float*          __restrict__ W_fc,
    const float*          __restrict__ b_fc,
    float*                __restrict__ out) {

    __shared__ __align__(16) char hq[2 * 16 * 512];   // 16 KB total

    const int tid = threadIdx.x;
    const int w   = tid >> 6, l = tid & 63;
    const int n   = l & 15,  lk = l >> 4;
    const int b0  = blockIdx.x * 16;
    const int jw  = w * 64;
    const float fs = scl[1];

    // loop-invariant LDS byte offsets (into buffer 0), kf-rotated per wave:
    // slot kx processes K-chunk kf = (kx + w) & 7.
    int rdA2[8];
    #pragma unroll
    for (int kx = 0; kx < 8; ++kx) {
        const int kf = (kx + w) & 7;
        const int g  = kf * 4 + lk;
        rdA2[kx] = n * 512 + ((g ^ n) << 4);
    }
    int wrA[4];
    #pragma unroll
    for (int tau = 0; tau < 4; ++tau) {
        const int j0 = jw + tau * 16 + lk * 4;
        wrA[tau] = n * 512 + (((j0 >> 4) ^ n) << 4) + (j0 & 15);
    }

    // per-lane EP base (this thread always reads the same 4 ushort4 slots of a row)
    const unsigned short* const epb = EP + jw + lk * 4;

    // ---- register-resident int8 A-frags, rotated to match rdA2 ----
    i32x4 af[4][8];
    #pragma unroll
    for (int tau = 0; tau < 4; ++tau)
        #pragma unroll
        for (int kx = 0; kx < 8; ++kx) {
            const int kf = (kx + w) & 7;
            af[tau][kx] = *reinterpret_cast<const i32x4*>(
                Wq + (size_t)(jw + tau * 16 + n) * HIDD + kf * 64 + lk * 16);
        }

    // ---- t = 0: h1 = tanh(EP[tok0]) -> buffer 1 ----
    {
        const int tok0 = x[b0 + n];
        #pragma unroll
        for (int tau = 0; tau < 4; ++tau) {
            const ushort4 v = *reinterpret_cast<const ushort4*>(
                epb + (size_t)tok0 * HIDD + tau * 16);
            *reinterpret_cast<unsigned*>(hq + 8192 + wrA[tau]) =
                pack4(q127b(bfu(v.x)), q127b(bfu(v.y)),
                      q127b(bfu(v.z)), q127b(bfu(v.w)));
        }
    }

    // ---- prefetch EP for t=1 (-> pcA) + token for t=2 (-> tokB) ----
    ushort4 pcA[4], pcB[4];
    int tokA, tokB;
    {
        const int tok1 = x[BATCH + b0 + n];
        #pragma unroll
        for (int tau = 0; tau < 4; ++tau)
            pcA[tau] = *reinterpret_cast<const ushort4*>(
                epb + (size_t)tok1 * HIDD + tau * 16);
    }
    tokB = x[2 * BATCH + b0 + n];
    __syncthreads();

// FIN: dequant + EP + tanh->q127 + perm-pack + b32 publish at write offset WO.
#define FIN(tau, acc, PC, WO)                                                 \
    {                                                                         \
        const unsigned q0 = q127b(fmaf((float)acc[0], fs, bfu(PC[tau].x)));   \
        const unsigned q1 = q127b(fmaf((float)acc[1], fs, bfu(PC[tau].y)));   \
        const unsigned q2 = q127b(fmaf((float)acc[2], fs, bfu(PC[tau].z)));   \
        const unsigned q3 = q127b(fmaf((float)acc[3], fs, bfu(PC[tau].w)));   \
        *reinterpret_cast<unsigned*>(hq + (WO) + wrA[tau]) = pack4(q0, q1, q2, q3); \
    }
// One RNN step. B-reads issue FIRST (earliest lgkm critical path; rotated
// addresses spread the post-barrier burst), then EP/token prefetch (vmem),
// then the MFMA block under setprio(1), then FIN, then LDS-only barrier.
#define STEP(ro, wo, PC, PN, TOKIN, TOKOUT, TNEXT)                            \
    {                                                                         \
        i32x4 B[8];                                                           \
        _Pragma("unroll")                                                     \
        for (int kx = 0; kx < 8; ++kx)                                        \
            B[kx] = *reinterpret_cast<const i32x4*>(hq + (ro) + rdA2[kx]);    \
        _Pragma("unroll")                                                     \
        for (int tau = 0; tau < 4; ++tau)                                     \
            PN[tau] = *reinterpret_cast<const ushort4*>(                      \
                epb + (size_t)(TOKIN) * HIDD + tau * 16);                     \
        const int tn_ = (TNEXT) > 511 ? 511 : (TNEXT);                        \
        TOKOUT = x[tn_ * BATCH + b0 + n];                                     \
        i32x4 a0 = {0,0,0,0}, a1 = {0,0,0,0}, a2 = {0,0,0,0}, a3 = {0,0,0,0}; \
        __builtin_amdgcn_s_setprio(1);                                        \
        _Pragma("unroll")                                                     \
        for (int kx = 0; kx < 8; ++kx) {                                      \
            a0 = __builtin_amdgcn_mfma_i32_16x16x64_i8(af[0][kx], B[kx], a0, 0, 0, 0); \
            a1 = __builtin_amdgcn_mfma_i32_16x16x64_i8(af[1][kx], B[kx], a1, 0, 0, 0); \
            a2 = __builtin_amdgcn_mfma_i32_16x16x64_i8(af[2][kx], B[kx], a2, 0, 0, 0); \
            a3 = __builtin_amdgcn_mfma_i32_16x16x64_i8(af[3][kx], B[kx], a3, 0, 0, 0); \
        }                                                                     \
        __builtin_amdgcn_s_setprio(0);                                        \
        FIN(0, a0, PC, wo) FIN(1, a1, PC, wo)                                 \
        FIN(2, a2, PC, wo) FIN(3, a3, PC, wo)                                 \
        lds_barrier();                                                        \
    }

    for (int tp = 0; tp < 256; ++tp) {
        const int t = 2 * tp + 1;              // 1,3,...,511
        // odd step: read buf1, write buf0; uses pcA, prefetch -> pcB
        STEP(8192, 0, pcA, pcB, tokB, tokA, t + 2)
        if (t == 511) break;
        // even step: read buf0, write buf1; uses pcB, prefetch -> pcA
        STEP(0, 8192, pcB, pcA, tokA, tokB, t + 3)
    }
#undef STEP
#undef FIN

    // ---- FC epilogue: h_512 is in buffer 0 (last write of t=511) ----
    if (tid < 256) {
        const int n2 = tid >> 4, c = tid & 15;
        float dot = 0.f;
        for (int g = 0; g < 32; ++g) {
            const char* p = hq + n2 * 512 + ((g ^ n2) << 4);
            const float* wf = W_fc + c * HIDD + g * 16;
            #pragma unroll
            for (int i = 0; i < 16; ++i)
                dot += (float)((signed char)p[i]) * wf[i];
        }
        out[(b0 + n2) * NCLS + c] = dot * (1.f / 127.f) + b_fc[c];
    }
}

// ---------------------------------------------------------------------------
// Tier-C fallback (round-1, known good) for small ws.
__global__ void cvt_kernel(const float* __restrict__ W_ih,
                           const float* __restrict__ W_hh,
                           const float* __restrict__ b_ih,
                           const float* __restrict__ b_hh,
                           unsigned short* __restrict__ Wpk,
                           unsigned short* __restrict__ Wipk,
                           float* __restrict__ bias) {
    const int NW = HIDD * HIDD;
    const int NI = HIDD * EMBD;
    int gid = blockIdx.x * blockDim.x + threadIdx.x;
    if (gid < NW) {
        int j = gid >> 9, k = gid & (HIDD - 1);
        Wpk[((k >> 2) * HIDD + j) * 4 + (k & 3)] = f2bf(W_hh[gid]);
    } else if (gid < NW + NI) {
        int g2 = gid - NW, j = g2 >> 8, e = g2 & (EMBD - 1);
        Wipk[((e >> 2) * HIDD + j) * 4 + (e & 3)] = f2bf(W_ih[g2]);
    } else if (gid < NW + NI + HIDD) {
        int j = gid - NW - NI;
        bias[j] = b_ih[j] + b_hh[j];
    }
}

__global__ __launch_bounds__(512) void rnn_kernel(
    const int* __restrict__ x, const float* __restrict__ emb,
    const unsigned short* __restrict__ Wpk, const unsigned short* __restrict__ Wipk,
    const float* __restrict__ bias, const float* __restrict__ W_fc,
    const float* __restrict__ b_fc, float* __restrict__ out) {
    __shared__ __align__(16) float hL[HIDD];
    __shared__ __align__(16) float xe[EMBD];
    __shared__ float red[512];
    const int tid = threadIdx.x, b = blockIdx.x, j = tid;
    hL[j] = 0.0f;
    const float bj = bias[j];
    const ushort4* Wp4 = reinterpret_cast<const ushort4*>(Wpk);
    const ushort4* Wi4 = reinterpret_cast<const ushort4*>(Wipk);
    for (int t = 0; t < SEQ; ++t) {
        const int tok = x[t * BATCH + b];
        if (tid < EMBD) xe[tid] = emb[tok * EMBD + tid];
        __syncthreads();
        float a0 = bj, a1 = 0.0f;
        #pragma unroll 8
        for (int e4 = 0; e4 < EMBD / 4; ++e4) {
            const float4 xv = *reinterpret_cast<const float4*>(&xe[e4 * 4]);
            const ushort4 ww = Wi4[e4 * HIDD + j];
            a0 += xv.x * bfu(ww.x) + xv.y * bfu(ww.y);
            a1 += xv.z * bfu(ww.z) + xv.w * bfu(ww.w);
        }
        #pragma unroll 8
        for (int k4 = 0; k4 < HIDD / 4; ++k4) {
            const float4 hvv = *reinterpret_cast<const float4*>(&hL[k4 * 4]);
            const ushort4 ww = Wp4[k4 * HIDD + j];
            a0 += hvv.x * bfu(ww.x) + hvv.y * bfu(ww.y);
            a1 += hvv.z * bfu(ww.z) + hvv.w * bfu(ww.w);
        }
        __syncthreads();
        hL[j] = tanhf(a0 + a1);
    }
    __syncthreads();
    {
        const int c = tid >> 5, ks = tid & 31;
        float p = 0.0f;
        #pragma unroll
        for (int jj = 0; jj < HIDD / 32; ++jj) {
            const int jd = ks * (HIDD / 32) + jj;
            p += hL[jd] * W_fc[c * HIDD + jd];
        }
        red[tid] = p;
        __syncthreads();
        if (tid < NCLS) {
            float ss = b_fc[tid];
            #pragma unroll
            for (int i = 0; i < 32; ++i) ss += red[tid * 32 + i];
            out[b * NCLS + tid] = ss;
        }
    }
}

// ---------------------------------------------------------------------------
extern "C" void kernel_launch(void* const* d_in, const int* in_sizes, int n_in,
                              void* d_out, int out_size, void* d_ws, size_t ws_size,
                              hipStream_t stream) {
    const int*   x    = (const int*)  d_in[0];
    const float* emb  = (const float*)d_in[1];
    const float* W_ih = (const float*)d_in[2];
    const float* W_hh = (const float*)d_in[3];
    const float* b_ih = (const float*)d_in[4];
    const float* b_hh = (const float*)d_in[5];
    const float* W_fc = (const float*)d_in[6];
    const float* b_fc = (const float*)d_in[7];
    float* out = (float*)d_out;

    const size_t QW_B  = (size_t)HIDD * HIDD;       // 256 KB int8 W_hh
    const size_t SCL_B = 16;                        // scale slots
    const size_t WIH_B = (size_t)HIDD * EMBD * 2;   // 256 KB bf16 W_ih
    const size_t EPN   = (size_t)VOCAB * HIDD;
    const size_t HEAD  = QW_B + SCL_B + WIH_B;

    if (ws_size >= HEAD + EPN * 2) {
        signed char*    Wq    = (signed char*)d_ws;
        float*          scl   = (float*)((char*)d_ws + QW_B);
        unsigned short* Wih_b = (unsigned short*)((char*)d_ws + QW_B + SCL_B);
        unsigned short* EP    = (unsigned short*)((char*)d_ws + HEAD);
        init_scl<<<1, 64, 0, stream>>>(scl);
        absmax_whh2<<<64, 256, 0, stream>>>(W_hh, scl);
        prep_weights<<<(HIDD * HIDD + HIDD * EMBD) / 256, 256, 0, stream>>>(
            W_hh, W_ih, scl, Wq, Wih_b);
        ep_gemm3<<<VOCAB / 64, 256, 0, stream>>>(emb, Wih_b, b_ih, b_hh, EP);
        rnn13<<<8, 512, 0, stream>>>(x, Wq, scl, EP, W_fc, b_fc, out);
    } else {
        unsigned short* Wpk  = (unsigned short*)d_ws;
        unsigned short* Wipk = Wpk + HIDD * HIDD;
        float*          bias = (float*)(Wipk + HIDD * EMBD);
        const int total = HIDD * HIDD + HIDD * EMBD + HIDD;
        cvt_kernel<<<(total + 255) / 256, 256, 0, stream>>>(W_ih, W_hh, b_ih, b_hh, Wpk, Wipk, bias);
        rnn_kernel<<<BATCH, 512, 0, stream>>>(x, emb, Wpk, Wipk, bias, W_fc, b_fc, out);
    }
}

// Round 14
// 785.200 us; speedup vs baseline: 1.1854x; 1.1557x over previous
//
#include <hip/hip_runtime.h>
#include <hip/hip_bf16.h>

#define SEQ   512
#define BATCH 128
#define EMBD  256
#define HIDD  512
#define NCLS  16
#define VOCAB 32000

typedef unsigned long long u64;
typedef __attribute__((ext_vector_type(8))) short  short8;
typedef __attribute__((ext_vector_type(4))) float  f32x4;
typedef __attribute__((ext_vector_type(4))) int    i32x4;

__device__ __forceinline__ float bfu(unsigned short u) {
    return __uint_as_float(((unsigned int)u) << 16);
}
__device__ __forceinline__ unsigned short f2bf(float f) {
    __hip_bfloat16 h = __float2bfloat16(f);
    return *reinterpret_cast<unsigned short*>(&h);
}
__device__ __forceinline__ float rcp_fast(float x) {
    float r;
    asm("v_rcp_f32 %0, %1" : "=v"(r) : "v"(x));
    return r;
}
// byte0 of return = (i8)rint(127*tanh(x)).  No clamp needed: exp->inf => rcp->0
// => q=127; exp->0 => rcp(1)=1 => q=-127.  Magic-number rounding: fmaf result
// lies in [2^23,2^24) so RN gives the exact integer; byte0 = two's complement.
__device__ __forceinline__ unsigned q127b(float x) {
    const float e = __expf(x + x);
    const float r = rcp_fast(e + 1.f);
    const float f = fmaf(r, -254.f, 12583039.f);   // 12582912 + 127
    return __float_as_uint(f);
}
__device__ __forceinline__ unsigned pack4(unsigned a, unsigned b,
                                          unsigned c, unsigned d) {
    const unsigned lo = __builtin_amdgcn_perm(b, a, 0x0400u);      // [a0,b0,·,·]
    const unsigned hi = __builtin_amdgcn_perm(d, c, 0x0400u);      // [c0,d0,·,·]
    return __builtin_amdgcn_perm(hi, lo, 0x05040100u);             // [a0,b0,c0,d0]
}
__device__ __forceinline__ void ep_store(unsigned short* p, float v) { *p = f2bf(v); }

// LDS-only barrier: orders ds_read/ds_write across waves WITHOUT draining
// vmcnt — global (EP prefetch) loads stay in flight across the rendezvous.
__device__ __forceinline__ void lds_barrier() {
    __builtin_amdgcn_sched_barrier(0);
    asm volatile("s_waitcnt lgkmcnt(0)" ::: "memory");
    __builtin_amdgcn_s_barrier();
    __builtin_amdgcn_sched_barrier(0);
}

// ---------------------------------------------------------------------------
// scl layout (floats): [0]=absmax, [1]=sW*sh, [2]=absmax bits (u32, atomicMax)
__global__ void init_scl(float* __restrict__ scl) {
    if (threadIdx.x == 0) reinterpret_cast<unsigned*>(scl)[2] = 0u;
}

__global__ __launch_bounds__(256) void absmax_whh2(const float* __restrict__ W,
                                                   float* __restrict__ scl) {
    __shared__ float red[256];
    float m = 0.f;
    for (int i = blockIdx.x * 256 + threadIdx.x; i < (HIDD * HIDD) / 4; i += 64 * 256) {
        const float4 v = reinterpret_cast<const float4*>(W)[i];
        m = fmaxf(m, fmaxf(fmaxf(fabsf(v.x), fabsf(v.y)),
                           fmaxf(fabsf(v.z), fabsf(v.w))));
    }
    red[threadIdx.x] = m;
    __syncthreads();
    for (int s = 128; s > 0; s >>= 1) {
        if (threadIdx.x < s) red[threadIdx.x] = fmaxf(red[threadIdx.x], red[threadIdx.x + s]);
        __syncthreads();
    }
    if (threadIdx.x == 0)
        atomicMax(reinterpret_cast<unsigned*>(scl) + 2, __float_as_uint(red[0]));
}

// W_hh fp32 -> int8 AND W_ih fp32 -> bf16 in one launch; thread 0 finalizes
// the scales. grid covers HIDD*HIDD + HIDD*EMBD elements.
__global__ void prep_weights(const float* __restrict__ W_hh,
                             const float* __restrict__ W_ih,
                             float* __restrict__ scl,
                             signed char* __restrict__ Wq,
                             unsigned short* __restrict__ Wb) {
    const int i = blockIdx.x * 256 + threadIdx.x;
    const float am = __uint_as_float(reinterpret_cast<unsigned*>(scl)[2]);
    if (i < HIDD * HIDD) {
        Wq[i] = (signed char)(int)rintf(W_hh[i] * (127.f / am));
    } else if (i < HIDD * HIDD + HIDD * EMBD) {
        const int j = i - HIDD * HIDD;
        Wb[j] = f2bf(W_ih[j]);
    }
    if (i == 0) { scl[0] = am; scl[1] = am / 16129.f; }   // (am/127)*(1/127)
}

// ---------------------------------------------------------------------------
// EP[v][j] = emb[v]·W_ih[j] + b_ih[j] + b_hh[j], stored bf16.  grid 500x256.
__global__ __launch_bounds__(256) void ep_gemm3(
    const float* __restrict__ emb, const unsigned short* __restrict__ Wih_b,
    const float* __restrict__ b_ih, const float* __restrict__ b_hh,
    unsigned short* __restrict__ EP) {
    const int w = threadIdx.x >> 6, l = threadIdx.x & 63;
    const int n = l & 15, lk = l >> 4;
    const int mtile = blockIdx.x * 4 + w;
    const int arow  = mtile * 16 + n;

    short8 areg[8];
    #pragma unroll
    for (int kk = 0; kk < 8; ++kk) {
        const int k0 = kk * 32 + lk * 8;
        const float4 a0 = *reinterpret_cast<const float4*>(emb + arow * EMBD + k0);
        const float4 a1 = *reinterpret_cast<const float4*>(emb + arow * EMBD + k0 + 4);
        short8 t;
        t[0]=(short)f2bf(a0.x); t[1]=(short)f2bf(a0.y); t[2]=(short)f2bf(a0.z); t[3]=(short)f2bf(a0.w);
        t[4]=(short)f2bf(a1.x); t[5]=(short)f2bf(a1.y); t[6]=(short)f2bf(a1.z); t[7]=(short)f2bf(a1.w);
        areg[kk] = t;
    }

    for (int nt = 0; nt < 32; ++nt) {
        const int col  = nt * 16 + n;
        const float bias = b_ih[col] + b_hh[col];
        f32x4 accA = {0.f,0.f,0.f,0.f}, accB = {0.f,0.f,0.f,0.f};
        #pragma unroll
        for (int kk = 0; kk < 8; ++kk) {
            const short8 bb = *reinterpret_cast<const short8*>(
                Wih_b + (size_t)col * EMBD + kk * 32 + lk * 8);
            if (kk & 1) accB = __builtin_amdgcn_mfma_f32_16x16x32_bf16(areg[kk], bb, accB, 0, 0, 0);
            else        accA = __builtin_amdgcn_mfma_f32_16x16x32_bf16(areg[kk], bb, accA, 0, 0, 0);
        }
        const f32x4 ac = accA + accB;
        #pragma unroll
        for (int r = 0; r < 4; ++r)
            ep_store(EP + (size_t)(mtile * 16 + lk * 4 + r) * HIDD + col, ac[r] + bias);
    }
}

// ---------------------------------------------------------------------------
// int8 weights-stationary RNN (r11 structure — best verified). grid = 8,
// 512 thr (8 waves, 2/SIMD). Wave w owns cols [w*64,w*64+64): all weights in
// 128 regs/thread (i8 A-frags). h int8 double-buffered in LDS (2 x 8 KB),
// 16B-granule XOR swizzle. LDS-only barrier; EP prefetch spans steps via
// alternating register sets; step pairs additionally unrolled 2x.
__global__ __launch_bounds__(512, 2) void rnn14(
    const int*            __restrict__ x,
    const signed char*    __restrict__ Wq,    // int8 [512][512]
    const float*          __restrict__ scl,   // [1] = sW*sh
    const unsigned short* __restrict__ EP,    // bf16 [VOCAB][512]
    const float*          __restrict__ W_fc,
    const float*          __restrict__ b_fc,
    float*                __restrict__ out) {

    __shared__ __align__(16) char hq[2 * 16 * 512];   // 16 KB total

    const int tid = threadIdx.x;
    const int w   = tid >> 6, l = tid & 63;
    const int n   = l & 15,  lk = l >> 4;
    const int b0  = blockIdx.x * 16;
    const int jw  = w * 64;
    const float fs = scl[1];

    // loop-invariant LDS byte offsets (into buffer 0)
    int rdA[8];
    #pragma unroll
    for (int kf = 0; kf < 8; ++kf) {
        const int g = kf * 4 + lk;
        rdA[kf] = n * 512 + ((g ^ n) << 4);
    }
    int wrA[4];
    #pragma unroll
    for (int tau = 0; tau < 4; ++tau) {
        const int j0 = jw + tau * 16 + lk * 4;
        wrA[tau] = n * 512 + (((j0 >> 4) ^ n) << 4) + (j0 & 15);
    }

    // per-lane EP base (this thread always reads the same 4 ushort4 slots of a row)
    const unsigned short* const epb = EP + jw + lk * 4;

    // ---- register-resident int8 A-frags: wave's 64 weight rows ----
    i32x4 af[4][8];
    #pragma unroll
    for (int tau = 0; tau < 4; ++tau)
        #pragma unroll
        for (int kf = 0; kf < 8; ++kf)
            af[tau][kf] = *reinterpret_cast<const i32x4*>(
                Wq + (size_t)(jw + tau * 16 + n) * HIDD + kf * 64 + lk * 16);

    // ---- t = 0: h1 = tanh(EP[tok0]) -> buffer 1 ----
    {
        const int tok0 = x[b0 + n];
        #pragma unroll
        for (int tau = 0; tau < 4; ++tau) {
            const ushort4 v = *reinterpret_cast<const ushort4*>(
                epb + (size_t)tok0 * HIDD + tau * 16);
            *reinterpret_cast<unsigned*>(hq + 8192 + wrA[tau]) =
                pack4(q127b(bfu(v.x)), q127b(bfu(v.y)),
                      q127b(bfu(v.z)), q127b(bfu(v.w)));
        }
    }

    // ---- prefetch EP for t=1 (-> pcA) + token for t=2 (-> tokB) ----
    ushort4 pcA[4], pcB[4];
    int tokA, tokB;
    {
        const int tok1 = x[BATCH + b0 + n];
        #pragma unroll
        for (int tau = 0; tau < 4; ++tau)
            pcA[tau] = *reinterpret_cast<const ushort4*>(
                epb + (size_t)tok1 * HIDD + tau * 16);
    }
    tokB = x[2 * BATCH + b0 + n];
    __syncthreads();

// FIN: dequant + EP + tanh->q127 + perm-pack + b32 publish at write offset WO.
#define FIN(tau, acc, PC, WO)                                                 \
    {                                                                         \
        const unsigned q0 = q127b(fmaf((float)acc[0], fs, bfu(PC[tau].x)));   \
        const unsigned q1 = q127b(fmaf((float)acc[1], fs, bfu(PC[tau].y)));   \
        const unsigned q2 = q127b(fmaf((float)acc[2], fs, bfu(PC[tau].z)));   \
        const unsigned q3 = q127b(fmaf((float)acc[3], fs, bfu(PC[tau].w)));   \
        *reinterpret_cast<unsigned*>(hq + (WO) + wrA[tau]) = pack4(q0, q1, q2, q3); \
    }
// One RNN step. ro/wo compile-time. PC = EP values for THIS step; PN = set to
// prefetch into (consumed next step); TOKIN = token whose EP row to prefetch;
// TOKOUT receives the token for two steps ahead.
#define STEP(ro, wo, PC, PN, TOKIN, TOKOUT, TNEXT)                            \
    {                                                                         \
        _Pragma("unroll")                                                     \
        for (int tau = 0; tau < 4; ++tau)                                     \
            PN[tau] = *reinterpret_cast<const ushort4*>(                      \
                epb + (size_t)(TOKIN) * HIDD + tau * 16);                     \
        const int tn_ = (TNEXT) > 511 ? 511 : (TNEXT);                        \
        TOKOUT = x[tn_ * BATCH + b0 + n];                                     \
        i32x4 B[8];                                                           \
        _Pragma("unroll")                                                     \
        for (int kf = 0; kf < 8; ++kf)                                        \
            B[kf] = *reinterpret_cast<const i32x4*>(hq + (ro) + rdA[kf]);     \
        i32x4 a0 = {0,0,0,0}, a1 = {0,0,0,0}, a2 = {0,0,0,0}, a3 = {0,0,0,0}; \
        _Pragma("unroll")                                                     \
        for (int kf = 0; kf < 8; ++kf) {                                      \
            a0 = __builtin_amdgcn_mfma_i32_16x16x64_i8(af[0][kf], B[kf], a0, 0, 0, 0); \
            a1 = __builtin_amdgcn_mfma_i32_16x16x64_i8(af[1][kf], B[kf], a1, 0, 0, 0); \
            a2 = __builtin_amdgcn_mfma_i32_16x16x64_i8(af[2][kf], B[kf], a2, 0, 0, 0); \
            a3 = __builtin_amdgcn_mfma_i32_16x16x64_i8(af[3][kf], B[kf], a3, 0, 0, 0); \
        }                                                                     \
        FIN(0, a0, PC, wo) FIN(1, a1, PC, wo)                                 \
        FIN(2, a2, PC, wo) FIN(3, a3, PC, wo)                                 \
        lds_barrier();                                                        \
    }

    #pragma unroll 2
    for (int tp = 0; tp < 256; ++tp) {
        const int t = 2 * tp + 1;              // 1,3,...,511
        // odd step: read buf1, write buf0; uses pcA, prefetch -> pcB
        STEP(8192, 0, pcA, pcB, tokB, tokA, t + 2)
        if (t == 511) break;
        // even step: read buf0, write buf1; uses pcB, prefetch -> pcA
        STEP(0, 8192, pcB, pcA, tokA, tokB, t + 3)
    }
#undef STEP
#undef FIN

    // ---- FC epilogue: h_512 is in buffer 0 (last write of t=511) ----
    if (tid < 256) {
        const int n2 = tid >> 4, c = tid & 15;
        float dot = 0.f;
        for (int g = 0; g < 32; ++g) {
            const char* p = hq + n2 * 512 + ((g ^ n2) << 4);
            const float* wf = W_fc + c * HIDD + g * 16;
            #pragma unroll
            for (int i = 0; i < 16; ++i)
                dot += (float)((signed char)p[i]) * wf[i];
        }
        out[(b0 + n2) * NCLS + c] = dot * (1.f / 127.f) + b_fc[c];
    }
}

// ---------------------------------------------------------------------------
// Tier-C fallback (round-1, known good) for small ws.
__global__ void cvt_kernel(const float* __restrict__ W_ih,
                           const float* __restrict__ W_hh,
                           const float* __restrict__ b_ih,
                           const float* __restrict__ b_hh,
                           unsigned short* __restrict__ Wpk,
                           unsigned short* __restrict__ Wipk,
                           float* __restrict__ bias) {
    const int NW = HIDD * HIDD;
    const int NI = HIDD * EMBD;
    int gid = blockIdx.x * blockDim.x + threadIdx.x;
    if (gid < NW) {
        int j = gid >> 9, k = gid & (HIDD - 1);
        Wpk[((k >> 2) * HIDD + j) * 4 + (k & 3)] = f2bf(W_hh[gid]);
    } else if (gid < NW + NI) {
        int g2 = gid - NW, j = g2 >> 8, e = g2 & (EMBD - 1);
        Wipk[((e >> 2) * HIDD + j) * 4 + (e & 3)] = f2bf(W_ih[g2]);
    } else if (gid < NW + NI + HIDD) {
        int j = gid - NW - NI;
        bias[j] = b_ih[j] + b_hh[j];
    }
}

__global__ __launch_bounds__(512) void rnn_kernel(
    const int* __restrict__ x, const float* __restrict__ emb,
    const unsigned short* __restrict__ Wpk, const unsigned short* __restrict__ Wipk,
    const float* __restrict__ bias, const float* __restrict__ W_fc,
    const float* __restrict__ b_fc, float* __restrict__ out) {
    __shared__ __align__(16) float hL[HIDD];
    __shared__ __align__(16) float xe[EMBD];
    __shared__ float red[512];
    const int tid = threadIdx.x, b = blockIdx.x, j = tid;
    hL[j] = 0.0f;
    const float bj = bias[j];
    const ushort4* Wp4 = reinterpret_cast<const ushort4*>(Wpk);
    const ushort4* Wi4 = reinterpret_cast<const ushort4*>(Wipk);
    for (int t = 0; t < SEQ; ++t) {
        const int tok = x[t * BATCH + b];
        if (tid < EMBD) xe[tid] = emb[tok * EMBD + tid];
        __syncthreads();
        float a0 = bj, a1 = 0.0f;
        #pragma unroll 8
        for (int e4 = 0; e4 < EMBD / 4; ++e4) {
            const float4 xv = *reinterpret_cast<const float4*>(&xe[e4 * 4]);
            const ushort4 ww = Wi4[e4 * HIDD + j];
            a0 += xv.x * bfu(ww.x) + xv.y * bfu(ww.y);
            a1 += xv.z * bfu(ww.z) + xv.w * bfu(ww.w);
        }
        #pragma unroll 8
        for (int k4 = 0; k4 < HIDD / 4; ++k4) {
            const float4 hvv = *reinterpret_cast<const float4*>(&hL[k4 * 4]);
            const ushort4 ww = Wp4[k4 * HIDD + j];
            a0 += hvv.x * bfu(ww.x) + hvv.y * bfu(ww.y);
            a1 += hvv.z * bfu(ww.z) + hvv.w * bfu(ww.w);
        }
        __syncthreads();
        hL[j] = tanhf(a0 + a1);
    }
    __syncthreads();
    {
        const int c = tid >> 5, ks = tid & 31;
        float p = 0.0f;
        #pragma unroll
        for (int jj = 0; jj < HIDD / 32; ++jj) {
            const int jd = ks * (HIDD / 32) + jj;
            p += hL[jd] * W_fc[c * HIDD + jd];
        }
        red[tid] = p;
        __syncthreads();
        if (tid < NCLS) {
            float ss = b_fc[tid];
            #pragma unroll
            for (int i = 0; i < 32; ++i) ss += red[tid * 32 + i];
            out[b * NCLS + tid] = ss;
        }
    }
}

// ---------------------------------------------------------------------------
extern "C" void kernel_launch(void* const* d_in, const int* in_sizes, int n_in,
                              void* d_out, int out_size, void* d_ws, size_t ws_size,
                              hipStream_t stream) {
    const int*   x    = (const int*)  d_in[0];
    const float* emb  = (const float*)d_in[1];
    const float* W_ih = (const float*)d_in[2];
    const float* W_hh = (const float*)d_in[3];
    const float* b_ih = (const float*)d_in[4];
    const float* b_hh = (const float*)d_in[5];
    const float* W_fc = (const float*)d_in[6];
    const float* b_fc = (const float*)d_in[7];
    float* out = (float*)d_out;

    const size_t QW_B  = (size_t)HIDD * HIDD;       // 256 KB int8 W_hh
    const size_t SCL_B = 16;                        // scale slots
    const size_t WIH_B = (size_t)HIDD * EMBD * 2;   // 256 KB bf16 W_ih
    const size_t EPN   = (size_t)VOCAB * HIDD;
    const size_t HEAD  = QW_B + SCL_B + WIH_B;

    if (ws_size >= HEAD + EPN * 2) {
        signed char*    Wq    = (signed char*)d_ws;
        float*          scl   = (float*)((char*)d_ws + QW_B);
        unsigned short* Wih_b = (unsigned short*)((char*)d_ws + QW_B + SCL_B);
        unsigned short* EP    = (unsigned short*)((char*)d_ws + HEAD);
        init_scl<<<1, 64, 0, stream>>>(scl);
        absmax_whh2<<<64, 256, 0, stream>>>(W_hh, scl);
        prep_weights<<<(HIDD * HIDD + HIDD * EMBD) / 256, 256, 0, stream>>>(
            W_hh, W_ih, scl, Wq, Wih_b);
        ep_gemm3<<<VOCAB / 64, 256, 0, stream>>>(emb, Wih_b, b_ih, b_hh, EP);
        rnn14<<<8, 512, 0, stream>>>(x, Wq, scl, EP, W_fc, b_fc, out);
    } else {
        unsigned short* Wpk  = (unsigned short*)d_ws;
        unsigned short* Wipk = Wpk + HIDD * HIDD;
        float*          bias = (float*)(Wipk + HIDD * EMBD);
        const int total = HIDD * HIDD + HIDD * EMBD + HIDD;
        cvt_kernel<<<(total + 255) / 256, 256, 0, stream>>>(W_ih, W_hh, b_ih, b_hh, Wpk, Wipk, bias);
        rnn_kernel<<<BATCH, 512, 0, stream>>>(x, emb, Wpk, Wipk, bias, W_fc, b_fc, out);
    }
}